// Round 1
// baseline (22312.653 us; speedup 1.0000x reference)
//
#include <hip/hip_runtime.h>
#include <cstdint>

#define THRESH 0.8f
#define RR2    2.25f
#define KMAX   4096
#define ROUNDS 32
#define MAXN   204800

// counters layout (ints): [0]=keptCnt [1]=cntUnassigned [2]=G [3]=hasUn [8+r]=uCnt[r]
#define C_KEPT  0
#define C_UN    1
#define C_G     2
#define C_HASUN 3
#define C_U0    8

// f32, no FMA contraction, left-assoc: matches numpy/XLA (x*x + y*y) + z*z
__device__ __forceinline__ float dist2(const float4 a, const float4 b) {
#pragma clang fp contract(off)
  float dx = a.x - b.x;
  float dy = a.y - b.y;
  float dz = a.z - b.z;
  return dx * dx + dy * dy + dz * dz;
}

// does d (higher priority?) block c: same seg, within radius, (beta desc, idx asc) strictly higher
__device__ __forceinline__ bool is_blocker(const float4 d, int didx, int dseg,
                                           const float4 c, int cidx, int cseg) {
  if (dseg != cseg) return false;
  if (dist2(d, c) > RR2) return false;
  return (d.w > c.w) || (d.w == c.w && didx < cidx);
}

__global__ void k_init(int* counters, int* cntKept, int* groupCount, int* keptList) {
  int i = blockIdx.x * blockDim.x + threadIdx.x;
  if (i < 64) counters[i] = 0;
  if (i < KMAX) { cntKept[i] = 0; keptList[i] = -1; }
  if (i < KMAX + 2) groupCount[i] = 0;
}

__global__ void k_compact(const float* __restrict__ betas, const float* __restrict__ cc,
                          const int* __restrict__ rs, int nrs, int N,
                          float4* __restrict__ cand, int* __restrict__ candIdx,
                          int* __restrict__ candSeg, int* __restrict__ listA, int* mCnt) {
  int i = blockIdx.x * blockDim.x + threadIdx.x;
  if (i >= N) return;
  float b = betas[i];
  if (b >= THRESH) {
    int slot = atomicAdd(mCnt, 1);
    cand[slot] = make_float4(cc[3 * i], cc[3 * i + 1], cc[3 * i + 2], b);
    candIdx[slot] = i;
    int s = 0;
    for (int t = 1; t < nrs - 1; ++t) s += (i >= rs[t]) ? 1 : 0;
    candSeg[slot] = s;
    listA[slot] = slot;
  }
}

// One peeling round. In-place monotone updates: kept/suppressed decisions are final,
// stale reads only delay resolution (safe). keptList entries init to -1 so a slot whose
// count was bumped but entry not yet visible is skipped.
__global__ void k_round(const float4* __restrict__ cand, const int* __restrict__ candIdx,
                        const int* __restrict__ candSeg,
                        const int* __restrict__ listOld, const int* __restrict__ uOld,
                        int* __restrict__ listNew, int* uNew,
                        int* __restrict__ keptList, int* keptCnt) {
  int U = *uOld;
  if (U == 0) return;
  int K0 = *keptCnt;
  if (K0 > KMAX) K0 = KMAX;
  int stride = gridDim.x * blockDim.x;
  for (int t = blockIdx.x * blockDim.x + threadIdx.x; t < U; t += stride) {
    int c = listOld[t];
    float4 fc = cand[c];
    int cidx = candIdx[c], cseg = candSeg[c];
    bool supp = false;
    for (int j = 0; j < K0; ++j) {
      int d = keptList[j];
      if (d < 0) continue;
      if (is_blocker(cand[d], candIdx[d], candSeg[d], fc, cidx, cseg)) { supp = true; break; }
    }
    if (supp) continue;  // suppressed: drop (assignment handled globally later)
    bool wait = false;
    for (int t2 = 0; t2 < U; ++t2) {     // early exit on first undecided blocker
      int d = listOld[t2];
      if (is_blocker(cand[d], candIdx[d], candSeg[d], fc, cidx, cseg)) { wait = true; break; }
    }
    if (wait) {
      listNew[atomicAdd(uNew, 1)] = c;
    } else {
      int s = atomicAdd(keptCnt, 1);
      if (s < KMAX) keptList[s] = c;
    }
  }
}

// Exact sequential greedy on whatever is left after ROUNDS (expected: nothing).
__global__ void k_fallback(const float4* __restrict__ cand, const int* __restrict__ candIdx,
                           const int* __restrict__ candSeg,
                           const int* __restrict__ list, const int* __restrict__ uPtr,
                           int* keptList, int* keptCnt) {
  int U = *uPtr;
  if (U == 0) return;
  __shared__ int sKept[KMAX];
  __shared__ unsigned int sRem[MAXN / 32];
  __shared__ float rB[256];
  __shared__ int rT[256];
  __shared__ int rI[256];
  __shared__ int sK, sChosen, sSupp;
  int t = threadIdx.x;
  int K0 = *keptCnt;
  if (K0 > KMAX) K0 = KMAX;
  for (int j = t; j < K0; j += blockDim.x) sKept[j] = keptList[j];
  int nw = (U + 31) / 32;
  for (int j = t; j < nw; j += blockDim.x) sRem[j] = 0u;
  if (t == 0) sK = K0;
  __syncthreads();
  for (int iter = 0; iter < U; ++iter) {
    float bb = -1.f; int bt = -1; int bi = 0x7fffffff;
    for (int j = t; j < U; j += blockDim.x) {
      if ((sRem[j >> 5] >> (j & 31)) & 1u) continue;
      int c = list[j];
      float w = cand[c].w;
      int ix = candIdx[c];
      if (w > bb || (w == bb && ix < bi)) { bb = w; bt = j; bi = ix; }
    }
    rB[t] = bb; rT[t] = bt; rI[t] = bi;
    __syncthreads();
    if (t == 0) {
      float xb = -1.f; int xt = -1, xi = 0x7fffffff;
      for (int q = 0; q < (int)blockDim.x; ++q) {
        if (rT[q] < 0) continue;
        if (rB[q] > xb || (rB[q] == xb && rI[q] < xi)) { xb = rB[q]; xt = rT[q]; xi = rI[q]; }
      }
      sChosen = xt;
      if (xt >= 0) sRem[xt >> 5] |= (1u << (xt & 31));
      sSupp = 0;
    }
    __syncthreads();
    int ct = sChosen;
    if (ct < 0) break;
    int c = list[ct];
    float4 fc = cand[c];
    int cidx = candIdx[c], cseg = candSeg[c];
    int Know = sK;
    for (int j = t; j < Know; j += blockDim.x) {
      int d = sKept[j];
      if (is_blocker(cand[d], candIdx[d], candSeg[d], fc, cidx, cseg)) sSupp = 1;
    }
    __syncthreads();
    if (t == 0 && sSupp == 0 && sK < KMAX) { sKept[sK] = c; sK = sK + 1; }
    __syncthreads();
  }
  int Kf = sK;
  for (int j = t; j < Kf; j += blockDim.x) keptList[j] = sKept[j];
  if (t == 0) *keptCnt = Kf;
}

// Each point -> max-priority kept condensate within radius (same seg), or -1.
__global__ void k_assign(const float* __restrict__ cc, const int* __restrict__ rs, int nrs, int N,
                         const float4* __restrict__ cand, const int* __restrict__ candIdx,
                         const int* __restrict__ candSeg,
                         const int* __restrict__ keptList, const int* __restrict__ counters,
                         int* cntKept, int* countersW, int* __restrict__ assoInt,
                         int* __restrict__ keptPos) {
  int i = blockIdx.x * blockDim.x + threadIdx.x;
  if (i >= N) return;
  float4 p = make_float4(cc[3 * i], cc[3 * i + 1], cc[3 * i + 2], 0.f);
  int seg = 0;
  for (int t = 1; t < nrs - 1; ++t) seg += (i >= rs[t]) ? 1 : 0;
  int K = counters[C_KEPT];
  if (K > KMAX) K = KMAX;
  float bb = -1.f; int bidx = -1, bpos = -1;
  for (int j = 0; j < K; ++j) {
    int c = keptList[j];
    if (candSeg[c] != seg) continue;
    float4 f = cand[c];
    if (dist2(f, p) > RR2) continue;
    int idx = candIdx[c];
    if (bpos < 0 || f.w > bb || (f.w == bb && idx < bidx)) { bb = f.w; bidx = idx; bpos = j; }
  }
  if (bpos >= 0) {
    assoInt[i] = bidx;
    keptPos[i] = bpos;
    atomicAdd(&cntKept[bpos], 1);
  } else {
    assoInt[i] = -1;
    keptPos[i] = -1;
    atomicAdd(&countersW[C_UN], 1);
  }
}

// rank kept by original index (asso values ascending); group 0 = unassigned if present
__global__ void k_rank(const int* __restrict__ keptList, const int* __restrict__ candIdx,
                       int* counters, const int* __restrict__ cntKept,
                       int* __restrict__ rankOfKept, int* __restrict__ groupCount) {
  int K = counters[C_KEPT];
  if (K > KMAX) K = KMAX;
  int un = counters[C_UN];
  int hasUn = un > 0 ? 1 : 0;
  int gid = blockIdx.x * blockDim.x + threadIdx.x;
  int stride = gridDim.x * blockDim.x;
  if (gid == 0) {
    counters[C_HASUN] = hasUn;
    counters[C_G] = K + hasUn;
    if (hasUn) groupCount[0] = un;
  }
  for (int j = gid; j < K; j += stride) {
    int myIdx = candIdx[keptList[j]];
    int r = hasUn;
    for (int j2 = 0; j2 < K; ++j2)
      r += (candIdx[keptList[j2]] < myIdx) ? 1 : 0;
    rankOfKept[j] = r;
    groupCount[r] = cntKept[j];
  }
}

__global__ void k_pointrank(int N, const int* __restrict__ keptPos,
                            const int* __restrict__ rankOfKept,
                            const int* __restrict__ assoInt,
                            int* __restrict__ pointRank, float* __restrict__ outAsso) {
  int i = blockIdx.x * blockDim.x + threadIdx.x;
  if (i >= N) return;
  int p = keptPos[i];
  pointRank[i] = (p < 0) ? 0 : rankOfKept[p];
  outAsso[i] = (float)assoInt[i];
}

__global__ void k_scan(const int* __restrict__ counters, const int* __restrict__ groupCount,
                       int* __restrict__ starts) {
  if (blockIdx.x == 0 && threadIdx.x == 0) {
    int G = counters[C_G];
    int acc = 0;
    for (int g = 0; g < G; ++g) { starts[g] = acc; acc += groupCount[g]; }
  }
}

__global__ void k_psrs(int N, const int* __restrict__ counters, const int* __restrict__ starts,
                       float* __restrict__ outPsrs) {
  int p = blockIdx.x * blockDim.x + threadIdx.x;
  if (p > N) return;
  int G = counters[C_G];
  outPsrs[p] = (p < G) ? (float)starts[p] : (float)N;
}

// stable counting-sort scatter: one block per group, ballot prefix within chunks
__global__ void k_scatter(int N, const int* __restrict__ counters,
                          const int* __restrict__ pointRank, const int* __restrict__ starts,
                          int* __restrict__ order, float* __restrict__ outSids,
                          float* __restrict__ outBelongs) {
  int g = blockIdx.x;
  if (g >= counters[C_G]) return;
  int base = starts[g];
  __shared__ int wsum[4];
  int lane = threadIdx.x & 63, wv = threadIdx.x >> 6;
  for (int i0 = 0; i0 < N; i0 += 256) {
    int i = i0 + threadIdx.x;
    bool m = (i < N) && (pointRank[i] == g);
    unsigned long long bal = __ballot(m);
    int pw = __popcll(bal & ((1ull << lane) - 1ull));
    if (lane == 0) wsum[wv] = __popcll(bal);
    __syncthreads();
    int off = 0;
    for (int q = 0; q < wv; ++q) off += wsum[q];
    int tot = wsum[0] + wsum[1] + wsum[2] + wsum[3];
    if (m) {
      int pos = base + off + pw;
      order[pos] = i;
      outSids[pos] = (float)i;
      outBelongs[pos] = (float)g;
    }
    base += tot;
    __syncthreads();
  }
}

__global__ void k_gather(const float* __restrict__ data, const int* __restrict__ order,
                         int F, float* __restrict__ out) {
  int row = blockIdx.x;
  int src = order[row];
  for (int f = threadIdx.x; f < F; f += blockDim.x)
    out[(size_t)row * F + f] = data[(size_t)src * F + f];
}

extern "C" void kernel_launch(void* const* d_in, const int* in_sizes, int n_in,
                              void* d_out, int out_size, void* d_ws, size_t ws_size,
                              hipStream_t stream) {
  const float* data  = (const float*)d_in[0];
  const float* cc    = (const float*)d_in[1];
  const float* betas = (const float*)d_in[2];
  const int*   rs    = (const int*)d_in[3];
  int nrs = in_sizes[3];
  int N   = in_sizes[2];           // betas is (N,1)
  int F   = in_sizes[0] / N;       // 128

  float* out = (float*)d_out;
  float* outSdata   = out;
  float* outPsrs    = outSdata + (size_t)N * F;
  float* outSids    = outPsrs + (N + 1);
  float* outAsso    = outSids + N;
  float* outBelongs = outAsso + N;

  char* p = (char*)d_ws;
  auto alloc = [&](size_t bytes) { void* r = (void*)p; p += (bytes + 255) & ~(size_t)255; return r; };
  int*    counters   = (int*)alloc(64 * 4);
  float4* cand       = (float4*)alloc((size_t)N * 16);
  int*    candIdx    = (int*)alloc((size_t)N * 4);
  int*    candSeg    = (int*)alloc((size_t)N * 4);
  int*    listA      = (int*)alloc((size_t)N * 4);
  int*    listB      = (int*)alloc((size_t)N * 4);
  int*    keptList   = (int*)alloc(KMAX * 4);
  int*    rankOfKept = (int*)alloc(KMAX * 4);
  int*    cntKept    = (int*)alloc(KMAX * 4);
  int*    groupCount = (int*)alloc((KMAX + 2) * 4);
  int*    starts     = (int*)alloc((KMAX + 2) * 4);
  int*    assoInt    = (int*)alloc((size_t)N * 4);
  int*    keptPos    = (int*)alloc((size_t)N * 4);
  int*    pointRank  = (int*)alloc((size_t)N * 4);
  int*    order      = (int*)alloc((size_t)N * 4);

  int nb = (N + 255) / 256;

  k_init<<<(KMAX + 2 + 255) / 256, 256, 0, stream>>>(counters, cntKept, groupCount, keptList);

  k_compact<<<nb, 256, 0, stream>>>(betas, cc, rs, nrs, N, cand, candIdx, candSeg,
                                    listA, &counters[C_U0]);

  for (int r = 0; r < ROUNDS; ++r) {
    const int* lo = (r % 2 == 0) ? listA : listB;
    int*       ln = (r % 2 == 0) ? listB : listA;
    k_round<<<256, 256, 0, stream>>>(cand, candIdx, candSeg, lo, &counters[C_U0 + r],
                                     ln, &counters[C_U0 + r + 1], keptList, &counters[C_KEPT]);
  }
  const int* finalList = (ROUNDS % 2 == 0) ? listA : listB;
  k_fallback<<<1, 256, 0, stream>>>(cand, candIdx, candSeg, finalList,
                                    &counters[C_U0 + ROUNDS], keptList, &counters[C_KEPT]);

  k_assign<<<nb, 256, 0, stream>>>(cc, rs, nrs, N, cand, candIdx, candSeg, keptList,
                                   counters, cntKept, counters, assoInt, keptPos);

  k_rank<<<32, 256, 0, stream>>>(keptList, candIdx, counters, cntKept, rankOfKept, groupCount);

  k_pointrank<<<nb, 256, 0, stream>>>(N, keptPos, rankOfKept, assoInt, pointRank, outAsso);

  k_scan<<<1, 64, 0, stream>>>(counters, groupCount, starts);

  k_psrs<<<(N + 256) / 256, 256, 0, stream>>>(N, counters, starts, outPsrs);

  k_scatter<<<KMAX + 1, 256, 0, stream>>>(N, counters, pointRank, starts, order,
                                          outSids, outBelongs);

  k_gather<<<N, 128, 0, stream>>>(data, order, F, outSdata);
}

// Round 2
// 8621.805 us; speedup vs baseline: 2.5879x; 2.5879x over previous
//
#include <hip/hip_runtime.h>
#include <cstdint>

#define THRESH 0.8f
#define RR2    2.25f
#define KMAX   4096
#define KLDS   2048
#define NB     4096   // beta buckets

// counters (ints): [0]=keptCnt [1]=cntUnassigned [2]=G [3]=hasUn [8]=U (candidate count)
#define C_KEPT  0
#define C_UN    1
#define C_G     2
#define C_HASUN 3
#define C_U0    8

// f32, no FMA contraction, left-assoc: matches numpy/XLA (x*x + y*y) + z*z
__device__ __forceinline__ float dist2(const float4 a, const float4 b) {
#pragma clang fp contract(off)
  float dx = a.x - b.x;
  float dy = a.y - b.y;
  float dz = a.z - b.z;
  return dx * dx + dy * dy + dz * dz;
}

__global__ void k_init(int* counters, int* cntKept, int* groupCount,
                       int* bucketCnt, int* bucketFill) {
  int i = blockIdx.x * blockDim.x + threadIdx.x;
  if (i < 64) counters[i] = 0;
  if (i < KMAX) cntKept[i] = 0;
  if (i < KMAX + 2) groupCount[i] = 0;
  if (i < NB) { bucketCnt[i] = 0; bucketFill[i] = 0; }
}

__device__ __forceinline__ int beta_bucket(float b) {
  int t = (int)((b - 0.8f) * 20480.0f);   // [0.8,1) -> [0,4096)
  return t < 0 ? 0 : (t > NB - 1 ? NB - 1 : t);
}

__global__ void k_compact(const float* __restrict__ betas, const float* __restrict__ cc,
                          const int* __restrict__ rs, int nrs, int N,
                          float4* __restrict__ ucand, int* __restrict__ uidx,
                          int* __restrict__ useg, int* __restrict__ ubkt,
                          int* bucketCnt, int* mCnt) {
  int i = blockIdx.x * blockDim.x + threadIdx.x;
  if (i >= N) return;
  float b = betas[i];
  if (b >= THRESH) {
    int slot = atomicAdd(mCnt, 1);
    ucand[slot] = make_float4(cc[3 * i], cc[3 * i + 1], cc[3 * i + 2], b);
    uidx[slot] = i;
    int s = 0;
    for (int t = 1; t < nrs - 1; ++t) s += (i >= rs[t]) ? 1 : 0;
    useg[slot] = s;
    int bk = beta_bucket(b);
    ubkt[slot] = bk;
    atomicAdd(&bucketCnt[bk], 1);
  }
}

// bucketStart[b] = count of candidates in buckets strictly ABOVE b (descending layout)
__global__ void k_bucketscan(const int* __restrict__ bucketCnt, int* __restrict__ bucketStart) {
  __shared__ int partial[256];
  int t = threadIdx.x;
  int sum = 0;
  for (int q = 0; q < 16; ++q) sum += bucketCnt[NB - 1 - (t * 16 + q)];
  partial[t] = sum;
  __syncthreads();
  if (t == 0) {
    int acc = 0;
    for (int i = 0; i < 256; ++i) { int v = partial[i]; partial[i] = acc; acc += v; }
  }
  __syncthreads();
  int acc = partial[t];
  for (int q = 0; q < 16; ++q) {
    int b = NB - 1 - (t * 16 + q);
    bucketStart[b] = acc;
    acc += bucketCnt[b];
  }
}

__global__ void k_bucketscatter(const int* __restrict__ counters,
                                const float4* __restrict__ ucand, const int* __restrict__ uidx,
                                const int* __restrict__ useg, const int* __restrict__ ubkt,
                                const int* __restrict__ bucketStart, int* bucketFill,
                                float4* __restrict__ scand, int* __restrict__ sidx,
                                int* __restrict__ sseg) {
  int i = blockIdx.x * blockDim.x + threadIdx.x;
  if (i >= counters[C_U0]) return;
  int b = ubkt[i];
  int pos = bucketStart[b] + atomicAdd(&bucketFill[b], 1);
  scand[pos] = ucand[i];
  sidx[pos] = uidx[i];
  sseg[pos] = useg[i];
}

// one thread per bucket: insertion sort by (beta desc, idx asc) -> exact global order
__global__ void k_bucketsort(const int* __restrict__ bucketCnt, const int* __restrict__ bucketStart,
                             float4* __restrict__ scand, int* __restrict__ sidx,
                             int* __restrict__ sseg) {
  int b = blockIdx.x * blockDim.x + threadIdx.x;
  if (b >= NB) return;
  int start = bucketStart[b];
  int end = start + bucketCnt[b];
  for (int a = start + 1; a < end; ++a) {
    float4 v = scand[a]; int vi = sidx[a]; int vs = sseg[a];
    int p = a - 1;
    while (p >= start && (scand[p].w < v.w || (scand[p].w == v.w && sidx[p] > vi))) {
      scand[p + 1] = scand[p]; sidx[p + 1] = sidx[p]; sseg[p + 1] = sseg[p];
      --p;
    }
    scand[p + 1] = v; sidx[p + 1] = vi; sseg[p + 1] = vs;
  }
}

// Single-wave exact sequential greedy over the sorted candidate list.
__global__ void __launch_bounds__(64) k_greedy(
    const float4* __restrict__ scand, const int* __restrict__ sidx,
    const int* __restrict__ sseg, const int* __restrict__ counters,
    float4* __restrict__ keptCand, int* __restrict__ keptIdx, int* __restrict__ keptSeg,
    int* countersW) {
  __shared__ float4 kc[KLDS];
  __shared__ int ki[KLDS];
  __shared__ int ks[KLDS];
  int U = counters[C_U0];
  int lane = threadIdx.x;
  int K = 0;
  for (int base = 0; base < U; base += 64) {
    int t = base + lane;
    bool valid = t < U;
    float4 c = make_float4(0.f, 0.f, 0.f, 0.f);
    int cidx = 0, cseg = -1;
    if (valid) { c = scand[t]; cidx = sidx[t]; cseg = sseg[t]; }
    bool alive = valid;
    // check against kept so far (all earlier in greedy order); early-exit when all decided
    for (int j = 0; j < K; ++j) {
      if (__ballot(alive) == 0ull) break;
      float4 kf; int sg;
      if (j < KLDS) { kf = kc[j]; sg = ks[j]; }
      else          { kf = keptCand[j]; sg = keptSeg[j]; }
      if (alive && sg == cseg && dist2(kf, c) <= RR2) alive = false;
    }
    // intra-chunk sequential resolution (lane order == sorted order)
    unsigned long long am = __ballot(alive);
    while (am) {
      int i = __ffsll((long long)am) - 1;
      float cx = __shfl(c.x, i), cy = __shfl(c.y, i), cz = __shfl(c.z, i), cw = __shfl(c.w, i);
      int ii = __shfl(cidx, i), is = __shfl(cseg, i);
      float4 kf = make_float4(cx, cy, cz, cw);
      if (K < KMAX && lane == 0) {
        keptCand[K] = kf; keptIdx[K] = ii; keptSeg[K] = is;
        if (K < KLDS) { kc[K] = kf; ki[K] = ii; ks[K] = is; }
      }
      ++K;
      if (alive && lane > i && cseg == is && dist2(kf, c) <= RR2) alive = false;
      am = __ballot(alive);
      am &= ~((i < 63) ? ((1ull << (i + 1)) - 1ull) : ~0ull);
    }
    __syncthreads();  // single wave: cheap; orders lane-0 LDS writes vs next chunk reads
  }
  if (lane == 0) countersW[C_KEPT] = (K < KMAX) ? K : KMAX;
}

// Each point -> FIRST kept (greedy order) within radius, same segment; kept staged in LDS tiles.
__global__ void k_assign(const float* __restrict__ cc, const int* __restrict__ rs, int nrs, int N,
                         const float4* __restrict__ keptCand, const int* __restrict__ keptIdx,
                         const int* __restrict__ keptSeg, const int* __restrict__ counters,
                         int* cntKept, int* countersW, int* __restrict__ assoInt,
                         int* __restrict__ keptPos) {
  __shared__ float4 tk[1024];
  __shared__ int tsg[1024];
  __shared__ int tix[1024];
  int i = blockIdx.x * blockDim.x + threadIdx.x;
  int K = counters[C_KEPT];
  if (K > KMAX) K = KMAX;
  float4 p = make_float4(0.f, 0.f, 0.f, 0.f);
  int seg = 0;
  if (i < N) {
    p = make_float4(cc[3 * i], cc[3 * i + 1], cc[3 * i + 2], 0.f);
    for (int t = 1; t < nrs - 1; ++t) seg += (i >= rs[t]) ? 1 : 0;
  }
  int bidx = -1, bpos = -1;
  bool done = false;
  for (int base = 0; base < K; base += 1024) {
    int tc = K - base; if (tc > 1024) tc = 1024;
    __syncthreads();
    for (int j = threadIdx.x; j < tc; j += blockDim.x) {
      tk[j] = keptCand[base + j]; tsg[j] = keptSeg[base + j]; tix[j] = keptIdx[base + j];
    }
    __syncthreads();
    if (i < N && !done) {
      for (int j = 0; j < tc; ++j) {
        if (tsg[j] == seg && dist2(tk[j], p) <= RR2) {
          bpos = base + j; bidx = tix[j]; done = true; break;
        }
      }
    }
  }
  if (i >= N) return;
  if (bpos >= 0) {
    assoInt[i] = bidx;
    keptPos[i] = bpos;
    atomicAdd(&cntKept[bpos], 1);
  } else {
    assoInt[i] = -1;
    keptPos[i] = -1;
    atomicAdd(&countersW[C_UN], 1);
  }
}

// rank kept by original index (asso values ascending); group 0 = unassigned if present
__global__ void k_rank(const int* __restrict__ keptIdx, int* counters,
                       const int* __restrict__ cntKept,
                       int* __restrict__ rankOfKept, int* __restrict__ groupCount) {
  int K = counters[C_KEPT];
  if (K > KMAX) K = KMAX;
  int un = counters[C_UN];
  int hasUn = un > 0 ? 1 : 0;
  int gid = blockIdx.x * blockDim.x + threadIdx.x;
  int stride = gridDim.x * blockDim.x;
  if (gid == 0) {
    counters[C_HASUN] = hasUn;
    counters[C_G] = K + hasUn;
    if (hasUn) groupCount[0] = un;
  }
  for (int j = gid; j < K; j += stride) {
    int myIdx = keptIdx[j];
    int r = hasUn;
    for (int j2 = 0; j2 < K; ++j2)
      r += (keptIdx[j2] < myIdx) ? 1 : 0;
    rankOfKept[j] = r;
    groupCount[r] = cntKept[j];
  }
}

__global__ void k_pointrank(int N, const int* __restrict__ keptPos,
                            const int* __restrict__ rankOfKept,
                            const int* __restrict__ assoInt,
                            int* __restrict__ pointRank, float* __restrict__ outAsso) {
  int i = blockIdx.x * blockDim.x + threadIdx.x;
  if (i >= N) return;
  int p = keptPos[i];
  pointRank[i] = (p < 0) ? 0 : rankOfKept[p];
  outAsso[i] = (float)assoInt[i];
}

__global__ void k_scan(const int* __restrict__ counters, const int* __restrict__ groupCount,
                       int* __restrict__ starts) {
  if (blockIdx.x == 0 && threadIdx.x == 0) {
    int G = counters[C_G];
    int acc = 0;
    for (int g = 0; g < G; ++g) { starts[g] = acc; acc += groupCount[g]; }
  }
}

__global__ void k_psrs(int N, const int* __restrict__ counters, const int* __restrict__ starts,
                       float* __restrict__ outPsrs) {
  int p = blockIdx.x * blockDim.x + threadIdx.x;
  if (p > N) return;
  int G = counters[C_G];
  outPsrs[p] = (p < G) ? (float)starts[p] : (float)N;
}

// stable counting-sort scatter: one block per group, ballot prefix within chunks
__global__ void k_scatter(int N, const int* __restrict__ counters,
                          const int* __restrict__ pointRank, const int* __restrict__ starts,
                          int* __restrict__ order, float* __restrict__ outSids,
                          float* __restrict__ outBelongs) {
  int g = blockIdx.x;
  if (g >= counters[C_G]) return;
  int base = starts[g];
  __shared__ int wsum[4];
  int lane = threadIdx.x & 63, wv = threadIdx.x >> 6;
  for (int i0 = 0; i0 < N; i0 += 256) {
    int i = i0 + threadIdx.x;
    bool m = (i < N) && (pointRank[i] == g);
    unsigned long long bal = __ballot(m);
    int pw = __popcll(bal & ((1ull << lane) - 1ull));
    if (lane == 0) wsum[wv] = __popcll(bal);
    __syncthreads();
    int off = 0;
    for (int q = 0; q < wv; ++q) off += wsum[q];
    int tot = wsum[0] + wsum[1] + wsum[2] + wsum[3];
    if (m) {
      int pos = base + off + pw;
      order[pos] = i;
      outSids[pos] = (float)i;
      outBelongs[pos] = (float)g;
    }
    base += tot;
    __syncthreads();
  }
}

__global__ void k_gather(const float* __restrict__ data, const int* __restrict__ order,
                         int F, float* __restrict__ out) {
  int row = blockIdx.x;
  int src = order[row];
  for (int f = threadIdx.x; f < F; f += blockDim.x)
    out[(size_t)row * F + f] = data[(size_t)src * F + f];
}

extern "C" void kernel_launch(void* const* d_in, const int* in_sizes, int n_in,
                              void* d_out, int out_size, void* d_ws, size_t ws_size,
                              hipStream_t stream) {
  const float* data  = (const float*)d_in[0];
  const float* cc    = (const float*)d_in[1];
  const float* betas = (const float*)d_in[2];
  const int*   rs    = (const int*)d_in[3];
  int nrs = in_sizes[3];
  int N   = in_sizes[2];           // betas is (N,1)
  int F   = in_sizes[0] / N;       // 128

  float* out = (float*)d_out;
  float* outSdata   = out;
  float* outPsrs    = outSdata + (size_t)N * F;
  float* outSids    = outPsrs + (N + 1);
  float* outAsso    = outSids + N;
  float* outBelongs = outAsso + N;

  char* p = (char*)d_ws;
  auto alloc = [&](size_t bytes) { void* r = (void*)p; p += (bytes + 255) & ~(size_t)255; return r; };
  int*    counters    = (int*)alloc(64 * 4);
  float4* ucand       = (float4*)alloc((size_t)N * 16);
  int*    uidx        = (int*)alloc((size_t)N * 4);
  int*    useg        = (int*)alloc((size_t)N * 4);
  int*    ubkt        = (int*)alloc((size_t)N * 4);
  float4* scand       = (float4*)alloc((size_t)N * 16);
  int*    sidx        = (int*)alloc((size_t)N * 4);
  int*    sseg        = (int*)alloc((size_t)N * 4);
  int*    bucketCnt   = (int*)alloc(NB * 4);
  int*    bucketStart = (int*)alloc(NB * 4);
  int*    bucketFill  = (int*)alloc(NB * 4);
  float4* keptCand    = (float4*)alloc(KMAX * 16);
  int*    keptIdx     = (int*)alloc(KMAX * 4);
  int*    keptSeg     = (int*)alloc(KMAX * 4);
  int*    rankOfKept  = (int*)alloc(KMAX * 4);
  int*    cntKept     = (int*)alloc(KMAX * 4);
  int*    groupCount  = (int*)alloc((KMAX + 2) * 4);
  int*    starts      = (int*)alloc((KMAX + 2) * 4);
  int*    assoInt     = (int*)alloc((size_t)N * 4);
  int*    keptPos     = (int*)alloc((size_t)N * 4);
  int*    pointRank   = (int*)alloc((size_t)N * 4);
  int*    order       = (int*)alloc((size_t)N * 4);

  int nb = (N + 255) / 256;

  k_init<<<(KMAX + 2 + 255) / 256, 256, 0, stream>>>(counters, cntKept, groupCount,
                                                     bucketCnt, bucketFill);

  k_compact<<<nb, 256, 0, stream>>>(betas, cc, rs, nrs, N, ucand, uidx, useg, ubkt,
                                    bucketCnt, &counters[C_U0]);

  k_bucketscan<<<1, 256, 0, stream>>>(bucketCnt, bucketStart);

  k_bucketscatter<<<nb, 256, 0, stream>>>(counters, ucand, uidx, useg, ubkt,
                                          bucketStart, bucketFill, scand, sidx, sseg);

  k_bucketsort<<<NB / 256, 256, 0, stream>>>(bucketCnt, bucketStart, scand, sidx, sseg);

  k_greedy<<<1, 64, 0, stream>>>(scand, sidx, sseg, counters,
                                 keptCand, keptIdx, keptSeg, counters);

  k_assign<<<nb, 256, 0, stream>>>(cc, rs, nrs, N, keptCand, keptIdx, keptSeg,
                                   counters, cntKept, counters, assoInt, keptPos);

  k_rank<<<32, 256, 0, stream>>>(keptIdx, counters, cntKept, rankOfKept, groupCount);

  k_pointrank<<<nb, 256, 0, stream>>>(N, keptPos, rankOfKept, assoInt, pointRank, outAsso);

  k_scan<<<1, 64, 0, stream>>>(counters, groupCount, starts);

  k_psrs<<<(N + 256) / 256, 256, 0, stream>>>(N, counters, starts, outPsrs);

  k_scatter<<<KMAX + 1, 256, 0, stream>>>(N, counters, pointRank, starts, order,
                                          outSids, outBelongs);

  k_gather<<<N, 128, 0, stream>>>(data, order, F, outSdata);
}

// Round 3
// 1694.461 us; speedup vs baseline: 13.1680x; 5.0882x over previous
//
#include <hip/hip_runtime.h>
#include <cstdint>

#define THRESH 0.8f
#define RR2    2.25f
#define KMAX   4096      // unified kept cap
#define KSEG   2048      // per-segment kept cap (LDS-resident in greedy)
#define NB     4096      // beta buckets per segment
#define NSEG_MAX 4
#define NBTOT  (NB * NSEG_MAX)

// counters (ints): [0]=keptCnt [1]=cntUnassigned [2]=G [3]=hasUn [8]=U (candidate count)
#define C_KEPT  0
#define C_UN    1
#define C_G     2
#define C_HASUN 3
#define C_U0    8

// f32, no FMA contraction, left-assoc: matches numpy/XLA (x*x + y*y) + z*z
__device__ __forceinline__ float dist2(const float4 a, const float4 b) {
#pragma clang fp contract(off)
  float dx = a.x - b.x;
  float dy = a.y - b.y;
  float dz = a.z - b.z;
  return dx * dx + dy * dy + dz * dz;
}

__global__ void k_init(int* counters, int* cntKept, int* groupCount,
                       int* bucketCnt, int* bucketFill) {
  int i = blockIdx.x * blockDim.x + threadIdx.x;
  if (i < 64) counters[i] = 0;
  if (i < KMAX) cntKept[i] = 0;
  if (i < KMAX + 2) groupCount[i] = 0;
  if (i < NBTOT) { bucketCnt[i] = 0; bucketFill[i] = 0; }
}

__device__ __forceinline__ int beta_bucket(float b) {
  int t = (int)((b - 0.8f) * 20480.0f);   // [0.8,1) -> [0,4096)
  return t < 0 ? 0 : (t > NB - 1 ? NB - 1 : t);
}

// ord-bucket = seg*NB + (NB-1 - beta_bucket): ascending ord == segment-major, beta-desc
__global__ void k_compact(const float* __restrict__ betas, const float* __restrict__ cc,
                          const int* __restrict__ rs, int nrs, int N,
                          float4* __restrict__ ucand, int* __restrict__ uidx,
                          int* __restrict__ ubkt, int* bucketCnt, int* mCnt) {
  int i = blockIdx.x * blockDim.x + threadIdx.x;
  if (i >= N) return;
  float b = betas[i];
  if (b >= THRESH) {
    int slot = atomicAdd(mCnt, 1);
    ucand[slot] = make_float4(cc[3 * i], cc[3 * i + 1], cc[3 * i + 2], b);
    uidx[slot] = i;
    int s = 0;
    for (int t = 1; t < nrs - 1; ++t) s += (i >= rs[t]) ? 1 : 0;
    int ord = s * NB + (NB - 1 - beta_bucket(b));
    ubkt[slot] = ord;
    atomicAdd(&bucketCnt[ord], 1);
  }
}

// ascending prefix sum over NBTOT ord-buckets; bucketStart[NBTOT] = total
__global__ void k_bucketscan(const int* __restrict__ bucketCnt, int* __restrict__ bucketStart) {
  __shared__ int partial[256];
  int t = threadIdx.x;
  const int PER = NBTOT / 256;   // 64
  int sum = 0;
  for (int q = 0; q < PER; ++q) sum += bucketCnt[t * PER + q];
  partial[t] = sum;
  __syncthreads();
  if (t == 0) {
    int acc = 0;
    for (int i = 0; i < 256; ++i) { int v = partial[i]; partial[i] = acc; acc += v; }
    bucketStart[NBTOT] = acc;
  }
  __syncthreads();
  int acc = partial[t];
  for (int q = 0; q < PER; ++q) {
    int b = t * PER + q;
    bucketStart[b] = acc;
    acc += bucketCnt[b];
  }
}

__global__ void k_bucketscatter(const int* __restrict__ counters,
                                const float4* __restrict__ ucand, const int* __restrict__ uidx,
                                const int* __restrict__ ubkt,
                                const int* __restrict__ bucketStart, int* bucketFill,
                                float4* __restrict__ scand, int* __restrict__ sidx) {
  int i = blockIdx.x * blockDim.x + threadIdx.x;
  if (i >= counters[C_U0]) return;
  int b = ubkt[i];
  int pos = bucketStart[b] + atomicAdd(&bucketFill[b], 1);
  scand[pos] = ucand[i];
  sidx[pos] = uidx[i];
}

// one thread per ord-bucket: insertion sort by (beta desc, idx asc) -> exact per-segment order
__global__ void k_bucketsort(const int* __restrict__ bucketCnt, const int* __restrict__ bucketStart,
                             float4* __restrict__ scand, int* __restrict__ sidx) {
  int b = blockIdx.x * blockDim.x + threadIdx.x;
  if (b >= NBTOT) return;
  int start = bucketStart[b];
  int end = start + bucketCnt[b];
  for (int a = start + 1; a < end; ++a) {
    float4 v = scand[a]; int vi = sidx[a];
    int p = a - 1;
    while (p >= start && (scand[p].w < v.w || (scand[p].w == v.w && sidx[p] > vi))) {
      scand[p + 1] = scand[p]; sidx[p + 1] = sidx[p];
      --p;
    }
    scand[p + 1] = v; sidx[p + 1] = vi;
  }
}

// Cooperative exact greedy: one block per segment, 16 waves.
// Waves 0..15 compute the 64xK kill matrix (strided over kept, LDS-broadcast reads);
// wave 0 resolves the chunk sequentially in lane order (== sorted order).
__global__ void __launch_bounds__(1024) k_greedy(
    const float4* __restrict__ scand, const int* __restrict__ sidx,
    const int* __restrict__ bucketStart,
    float4* __restrict__ segKeptCand, int* __restrict__ segKeptIdx,
    int* __restrict__ keptCntSeg) {
  __shared__ float4 kc[KSEG];                  // 32 KiB
  __shared__ unsigned long long killM[16];
  __shared__ int sK;
  int s = blockIdx.x;
  int base = bucketStart[s * NB];
  int U = bucketStart[(s + 1) * NB] - base;
  int lane = threadIdx.x & 63, w = threadIdx.x >> 6;
  if (threadIdx.x == 0) sK = 0;
  __syncthreads();
  for (int c0 = 0; c0 < U; c0 += 64) {
    int t = c0 + lane;
    bool valid = t < U;
    float4 c = make_float4(1e30f, 1e30f, 1e30f, 0.f);
    int cidx = 0;
    if (valid) { c = scand[base + t]; cidx = sidx[base + t]; }
    int K = sK; if (K > KSEG) K = KSEG;
    bool kill = false;
#pragma unroll 4
    for (int j = w; j < K; j += 16)
      if (dist2(kc[j], c) <= RR2) kill = true;   // invalid lanes: dist2=inf, never kills
    killM[w] = __ballot(kill);
    __syncthreads();
    if (w == 0) {
      unsigned long long killed = killM[0];
      for (int q = 1; q < 16; ++q) killed |= killM[q];
      bool alive = valid && !((killed >> lane) & 1ull);
      unsigned long long am = __ballot(alive);
      int Kl = sK;
      while (am) {
        int i = __ffsll((long long)am) - 1;
        float kx = __shfl(c.x, i), ky = __shfl(c.y, i), kz = __shfl(c.z, i), kw = __shfl(c.w, i);
        int ii = __shfl(cidx, i);
        float4 kf = make_float4(kx, ky, kz, kw);
        if (Kl < KSEG && lane == 0) {
          kc[Kl] = kf;
          segKeptCand[s * KSEG + Kl] = kf;
          segKeptIdx[s * KSEG + Kl] = ii;
        }
        ++Kl;
        if (alive && lane > i && dist2(kf, c) <= RR2) alive = false;
        am = __ballot(alive);
        am &= ~((i < 63) ? ((1ull << (i + 1)) - 1ull) : ~0ull);
      }
      if (lane == 0) sK = Kl;
    }
    __syncthreads();   // publishes sK and lane-0 kc[] writes to all waves
  }
  if (threadIdx.x == 0) keptCntSeg[s] = (sK < KSEG) ? sK : KSEG;
}

// unify per-segment kept lists (segment-major; order within segment = greedy order)
__global__ void k_merge(int nseg, const float4* __restrict__ segKeptCand,
                        const int* __restrict__ segKeptIdx, const int* __restrict__ keptCntSeg,
                        float4* __restrict__ keptCand, int* __restrict__ keptIdx,
                        int* __restrict__ segKeptStart, int* __restrict__ segKeptCnt,
                        int* counters) {
  __shared__ int pre[NSEG_MAX + 1];
  if (threadIdx.x == 0) {
    int acc = 0;
    for (int s2 = 0; s2 < nseg; ++s2) {
      pre[s2] = acc;
      int cn = keptCntSeg[s2]; if (cn > KSEG) cn = KSEG;
      acc += cn;
    }
    pre[nseg] = acc;
    counters[C_KEPT] = (acc < KMAX) ? acc : KMAX;
  }
  __syncthreads();
  for (int s2 = 0; s2 < nseg; ++s2) {
    int cn = keptCntSeg[s2]; if (cn > KSEG) cn = KSEG;
    if (threadIdx.x == 0) { segKeptStart[s2] = pre[s2]; segKeptCnt[s2] = cn; }
    for (int j = threadIdx.x; j < cn; j += blockDim.x) {
      keptCand[pre[s2] + j] = segKeptCand[s2 * KSEG + j];
      keptIdx[pre[s2] + j] = segKeptIdx[s2 * KSEG + j];
    }
  }
}

// Each point -> FIRST kept (greedy order, own segment) within radius; early exit.
__global__ void k_assign(const float* __restrict__ cc, const int* __restrict__ rs, int nrs, int N,
                         const float4* __restrict__ keptCand, const int* __restrict__ keptIdx,
                         const int* __restrict__ segKeptStart, const int* __restrict__ segKeptCnt,
                         int* cntKept, int* countersW, int* __restrict__ assoInt,
                         int* __restrict__ keptPos) {
  int i = blockIdx.x * blockDim.x + threadIdx.x;
  if (i >= N) return;
  float4 p = make_float4(cc[3 * i], cc[3 * i + 1], cc[3 * i + 2], 0.f);
  int seg = 0;
  for (int t = 1; t < nrs - 1; ++t) seg += (i >= rs[t]) ? 1 : 0;
  int ks = segKeptStart[seg];
  int kcnt = segKeptCnt[seg];
  int bidx = -1, bpos = -1;
  for (int j = 0; j < kcnt; ++j) {
    if (dist2(keptCand[ks + j], p) <= RR2) {
      bpos = ks + j; bidx = keptIdx[ks + j]; break;
    }
  }
  if (bpos >= 0) {
    assoInt[i] = bidx;
    keptPos[i] = bpos;
    atomicAdd(&cntKept[bpos], 1);
  } else {
    assoInt[i] = -1;
    keptPos[i] = -1;
    atomicAdd(&countersW[C_UN], 1);
  }
}

// rank kept by original index (asso values ascending); group 0 = unassigned if present
__global__ void k_rank(const int* __restrict__ keptIdx, int* counters,
                       const int* __restrict__ cntKept,
                       int* __restrict__ rankOfKept, int* __restrict__ groupCount) {
  int K = counters[C_KEPT];
  if (K > KMAX) K = KMAX;
  int un = counters[C_UN];
  int hasUn = un > 0 ? 1 : 0;
  int gid = blockIdx.x * blockDim.x + threadIdx.x;
  int stride = gridDim.x * blockDim.x;
  if (gid == 0) {
    counters[C_HASUN] = hasUn;
    counters[C_G] = K + hasUn;
    if (hasUn) groupCount[0] = un;
  }
  for (int j = gid; j < K; j += stride) {
    int myIdx = keptIdx[j];
    int r = hasUn;
    for (int j2 = 0; j2 < K; ++j2)
      r += (keptIdx[j2] < myIdx) ? 1 : 0;
    rankOfKept[j] = r;
    groupCount[r] = cntKept[j];
  }
}

__global__ void k_pointrank(int N, const int* __restrict__ keptPos,
                            const int* __restrict__ rankOfKept,
                            const int* __restrict__ assoInt,
                            int* __restrict__ pointRank, float* __restrict__ outAsso) {
  int i = blockIdx.x * blockDim.x + threadIdx.x;
  if (i >= N) return;
  int p = keptPos[i];
  pointRank[i] = (p < 0) ? 0 : rankOfKept[p];
  outAsso[i] = (float)assoInt[i];
}

__global__ void k_scan(const int* __restrict__ counters, const int* __restrict__ groupCount,
                       int* __restrict__ starts) {
  if (blockIdx.x == 0 && threadIdx.x == 0) {
    int G = counters[C_G];
    int acc = 0;
    for (int g = 0; g < G; ++g) { starts[g] = acc; acc += groupCount[g]; }
  }
}

__global__ void k_psrs(int N, const int* __restrict__ counters, const int* __restrict__ starts,
                       float* __restrict__ outPsrs) {
  int p = blockIdx.x * blockDim.x + threadIdx.x;
  if (p > N) return;
  int G = counters[C_G];
  outPsrs[p] = (p < G) ? (float)starts[p] : (float)N;
}

// stable counting-sort scatter: one block per group, ballot prefix within chunks
__global__ void k_scatter(int N, const int* __restrict__ counters,
                          const int* __restrict__ pointRank, const int* __restrict__ starts,
                          int* __restrict__ order, float* __restrict__ outSids,
                          float* __restrict__ outBelongs) {
  int g = blockIdx.x;
  if (g >= counters[C_G]) return;
  int base = starts[g];
  __shared__ int wsum[4];
  int lane = threadIdx.x & 63, wv = threadIdx.x >> 6;
  for (int i0 = 0; i0 < N; i0 += 256) {
    int i = i0 + threadIdx.x;
    bool m = (i < N) && (pointRank[i] == g);
    unsigned long long bal = __ballot(m);
    int pw = __popcll(bal & ((1ull << lane) - 1ull));
    if (lane == 0) wsum[wv] = __popcll(bal);
    __syncthreads();
    int off = 0;
    for (int q = 0; q < wv; ++q) off += wsum[q];
    int tot = wsum[0] + wsum[1] + wsum[2] + wsum[3];
    if (m) {
      int pos = base + off + pw;
      order[pos] = i;
      outSids[pos] = (float)i;
      outBelongs[pos] = (float)g;
    }
    base += tot;
    __syncthreads();
  }
}

__global__ void k_gather(const float* __restrict__ data, const int* __restrict__ order,
                         int F, float* __restrict__ out) {
  int row = blockIdx.x;
  int src = order[row];
  for (int f = threadIdx.x; f < F; f += blockDim.x)
    out[(size_t)row * F + f] = data[(size_t)src * F + f];
}

extern "C" void kernel_launch(void* const* d_in, const int* in_sizes, int n_in,
                              void* d_out, int out_size, void* d_ws, size_t ws_size,
                              hipStream_t stream) {
  const float* data  = (const float*)d_in[0];
  const float* cc    = (const float*)d_in[1];
  const float* betas = (const float*)d_in[2];
  const int*   rs    = (const int*)d_in[3];
  int nrs = in_sizes[3];
  int N   = in_sizes[2];           // betas is (N,1)
  int F   = in_sizes[0] / N;       // 128
  int nseg = nrs - 1; if (nseg < 1) nseg = 1; if (nseg > NSEG_MAX) nseg = NSEG_MAX;

  float* out = (float*)d_out;
  float* outSdata   = out;
  float* outPsrs    = outSdata + (size_t)N * F;
  float* outSids    = outPsrs + (N + 1);
  float* outAsso    = outSids + N;
  float* outBelongs = outAsso + N;

  char* p = (char*)d_ws;
  auto alloc = [&](size_t bytes) { void* r = (void*)p; p += (bytes + 255) & ~(size_t)255; return r; };
  int*    counters     = (int*)alloc(64 * 4);
  float4* ucand        = (float4*)alloc((size_t)N * 16);
  int*    uidx         = (int*)alloc((size_t)N * 4);
  int*    ubkt         = (int*)alloc((size_t)N * 4);
  float4* scand        = (float4*)alloc((size_t)N * 16);
  int*    sidx         = (int*)alloc((size_t)N * 4);
  int*    bucketCnt    = (int*)alloc(NBTOT * 4);
  int*    bucketStart  = (int*)alloc((NBTOT + 1) * 4);
  int*    bucketFill   = (int*)alloc(NBTOT * 4);
  float4* segKeptCand  = (float4*)alloc((size_t)NSEG_MAX * KSEG * 16);
  int*    segKeptIdx   = (int*)alloc((size_t)NSEG_MAX * KSEG * 4);
  int*    keptCntSeg   = (int*)alloc(NSEG_MAX * 4);
  int*    segKeptStart = (int*)alloc(NSEG_MAX * 4);
  int*    segKeptCnt   = (int*)alloc(NSEG_MAX * 4);
  float4* keptCand     = (float4*)alloc(KMAX * 16);
  int*    keptIdx      = (int*)alloc(KMAX * 4);
  int*    rankOfKept   = (int*)alloc(KMAX * 4);
  int*    cntKept      = (int*)alloc(KMAX * 4);
  int*    groupCount   = (int*)alloc((KMAX + 2) * 4);
  int*    starts       = (int*)alloc((KMAX + 2) * 4);
  int*    assoInt      = (int*)alloc((size_t)N * 4);
  int*    keptPos      = (int*)alloc((size_t)N * 4);
  int*    pointRank    = (int*)alloc((size_t)N * 4);
  int*    order        = (int*)alloc((size_t)N * 4);

  int nb = (N + 255) / 256;

  k_init<<<(NBTOT + 255) / 256, 256, 0, stream>>>(counters, cntKept, groupCount,
                                                  bucketCnt, bucketFill);

  k_compact<<<nb, 256, 0, stream>>>(betas, cc, rs, nrs, N, ucand, uidx, ubkt,
                                    bucketCnt, &counters[C_U0]);

  k_bucketscan<<<1, 256, 0, stream>>>(bucketCnt, bucketStart);

  k_bucketscatter<<<nb, 256, 0, stream>>>(counters, ucand, uidx, ubkt,
                                          bucketStart, bucketFill, scand, sidx);

  k_bucketsort<<<NBTOT / 256, 256, 0, stream>>>(bucketCnt, bucketStart, scand, sidx);

  k_greedy<<<nseg, 1024, 0, stream>>>(scand, sidx, bucketStart,
                                      segKeptCand, segKeptIdx, keptCntSeg);

  k_merge<<<1, 256, 0, stream>>>(nseg, segKeptCand, segKeptIdx, keptCntSeg,
                                 keptCand, keptIdx, segKeptStart, segKeptCnt, counters);

  k_assign<<<nb, 256, 0, stream>>>(cc, rs, nrs, N, keptCand, keptIdx,
                                   segKeptStart, segKeptCnt, cntKept, counters,
                                   assoInt, keptPos);

  k_rank<<<32, 256, 0, stream>>>(keptIdx, counters, cntKept, rankOfKept, groupCount);

  k_pointrank<<<nb, 256, 0, stream>>>(N, keptPos, rankOfKept, assoInt, pointRank, outAsso);

  k_scan<<<1, 64, 0, stream>>>(counters, groupCount, starts);

  k_psrs<<<(N + 256) / 256, 256, 0, stream>>>(N, counters, starts, outPsrs);

  k_scatter<<<KMAX + 1, 256, 0, stream>>>(N, counters, pointRank, starts, order,
                                          outSids, outBelongs);

  k_gather<<<N, 128, 0, stream>>>(data, order, F, outSdata);
}

// Round 4
// 1117.128 us; speedup vs baseline: 19.9732x; 1.5168x over previous
//
#include <hip/hip_runtime.h>
#include <cstdint>

#define THRESH 0.8f
#define RR2    2.25f
#define KMAX   4096      // unified kept cap
#define KSEG   2048      // per-segment kept cap (LDS-resident in greedy)
#define ALDS   2048      // kept staged in LDS for assign
#define NB     4096      // beta buckets per segment
#define NSEG_MAX 4
#define NBTOT  (NB * NSEG_MAX)

// counters (ints): [0]=keptCnt [1]=cntUnassigned [2]=G [3]=hasUn [8]=U (candidate count)
#define C_KEPT  0
#define C_UN    1
#define C_G     2
#define C_HASUN 3
#define C_U0    8

// f32, no FMA contraction, left-assoc: matches numpy/XLA (x*x + y*y) + z*z
__device__ __forceinline__ float dist2(const float4 a, const float4 b) {
#pragma clang fp contract(off)
  float dx = a.x - b.x;
  float dy = a.y - b.y;
  float dz = a.z - b.z;
  return dx * dx + dy * dy + dz * dz;
}

__global__ void k_init(int* counters, int* cntKept, int* groupCount,
                       int* bucketCnt, int* bucketFill) {
  int i = blockIdx.x * blockDim.x + threadIdx.x;
  if (i < 64) counters[i] = 0;
  if (i < KMAX) cntKept[i] = 0;
  if (i < KMAX + 2) groupCount[i] = 0;
  if (i < NBTOT) { bucketCnt[i] = 0; bucketFill[i] = 0; }
}

__device__ __forceinline__ int beta_bucket(float b) {
  int t = (int)((b - 0.8f) * 20480.0f);   // [0.8,1) -> [0,4096)
  return t < 0 ? 0 : (t > NB - 1 ? NB - 1 : t);
}

// ord-bucket = seg*NB + (NB-1 - beta_bucket): ascending ord == segment-major, beta-desc
__global__ void k_compact(const float* __restrict__ betas, const float* __restrict__ cc,
                          const int* __restrict__ rs, int nrs, int N,
                          float4* __restrict__ ucand, int* __restrict__ uidx,
                          int* __restrict__ ubkt, int* bucketCnt, int* mCnt) {
  int i = blockIdx.x * blockDim.x + threadIdx.x;
  if (i >= N) return;
  float b = betas[i];
  if (b >= THRESH) {
    int slot = atomicAdd(mCnt, 1);
    ucand[slot] = make_float4(cc[3 * i], cc[3 * i + 1], cc[3 * i + 2], b);
    uidx[slot] = i;
    int s = 0;
    for (int t = 1; t < nrs - 1; ++t) s += (i >= rs[t]) ? 1 : 0;
    int ord = s * NB + (NB - 1 - beta_bucket(b));
    ubkt[slot] = ord;
    atomicAdd(&bucketCnt[ord], 1);
  }
}

// ascending prefix sum over NBTOT ord-buckets; bucketStart[NBTOT] = total
__global__ void k_bucketscan(const int* __restrict__ bucketCnt, int* __restrict__ bucketStart) {
  __shared__ int partial[256];
  int t = threadIdx.x;
  const int PER = NBTOT / 256;   // 64
  int sum = 0;
  for (int q = 0; q < PER; ++q) sum += bucketCnt[t * PER + q];
  partial[t] = sum;
  __syncthreads();
  if (t == 0) {
    int acc = 0;
    for (int i = 0; i < 256; ++i) { int v = partial[i]; partial[i] = acc; acc += v; }
    bucketStart[NBTOT] = acc;
  }
  __syncthreads();
  int acc = partial[t];
  for (int q = 0; q < PER; ++q) {
    int b = t * PER + q;
    bucketStart[b] = acc;
    acc += bucketCnt[b];
  }
}

__global__ void k_bucketscatter(const int* __restrict__ counters,
                                const float4* __restrict__ ucand, const int* __restrict__ uidx,
                                const int* __restrict__ ubkt,
                                const int* __restrict__ bucketStart, int* bucketFill,
                                float4* __restrict__ scand, int* __restrict__ sidx) {
  int i = blockIdx.x * blockDim.x + threadIdx.x;
  if (i >= counters[C_U0]) return;
  int b = ubkt[i];
  int pos = bucketStart[b] + atomicAdd(&bucketFill[b], 1);
  scand[pos] = ucand[i];
  sidx[pos] = uidx[i];
}

// one thread per ord-bucket: insertion sort by (beta desc, idx asc) -> exact per-segment order
__global__ void k_bucketsort(const int* __restrict__ bucketCnt, const int* __restrict__ bucketStart,
                             float4* __restrict__ scand, int* __restrict__ sidx) {
  int b = blockIdx.x * blockDim.x + threadIdx.x;
  if (b >= NBTOT) return;
  int start = bucketStart[b];
  int end = start + bucketCnt[b];
  for (int a = start + 1; a < end; ++a) {
    float4 v = scand[a]; int vi = sidx[a];
    int p = a - 1;
    while (p >= start && (scand[p].w < v.w || (scand[p].w == v.w && sidx[p] > vi))) {
      scand[p + 1] = scand[p]; sidx[p + 1] = sidx[p];
      --p;
    }
    scand[p + 1] = v; sidx[p + 1] = vi;
  }
}

// Cooperative exact greedy: one block per segment, 16 waves.
__global__ void __launch_bounds__(1024) k_greedy(
    const float4* __restrict__ scand, const int* __restrict__ sidx,
    const int* __restrict__ bucketStart,
    float4* __restrict__ segKeptCand, int* __restrict__ segKeptIdx,
    int* __restrict__ keptCntSeg) {
  __shared__ float4 kc[KSEG];                  // 32 KiB
  __shared__ unsigned long long killM[16];
  __shared__ int sK;
  int s = blockIdx.x;
  int base = bucketStart[s * NB];
  int U = bucketStart[(s + 1) * NB] - base;
  int lane = threadIdx.x & 63, w = threadIdx.x >> 6;
  if (threadIdx.x == 0) sK = 0;
  __syncthreads();
  for (int c0 = 0; c0 < U; c0 += 64) {
    int t = c0 + lane;
    bool valid = t < U;
    float4 c = make_float4(1e30f, 1e30f, 1e30f, 0.f);
    int cidx = 0;
    if (valid) { c = scand[base + t]; cidx = sidx[base + t]; }
    int K = sK; if (K > KSEG) K = KSEG;
    bool kill = false;
#pragma unroll 4
    for (int j = w; j < K; j += 16)
      if (dist2(kc[j], c) <= RR2) kill = true;
    killM[w] = __ballot(kill);
    __syncthreads();
    if (w == 0) {
      unsigned long long killed = killM[0];
      for (int q = 1; q < 16; ++q) killed |= killM[q];
      bool alive = valid && !((killed >> lane) & 1ull);
      unsigned long long am = __ballot(alive);
      int Kl = sK;
      while (am) {
        int i = __ffsll((long long)am) - 1;
        float kx = __shfl(c.x, i), ky = __shfl(c.y, i), kz = __shfl(c.z, i), kw = __shfl(c.w, i);
        int ii = __shfl(cidx, i);
        float4 kf = make_float4(kx, ky, kz, kw);
        if (Kl < KSEG && lane == 0) {
          kc[Kl] = kf;
          segKeptCand[s * KSEG + Kl] = kf;
          segKeptIdx[s * KSEG + Kl] = ii;
        }
        ++Kl;
        if (alive && lane > i && dist2(kf, c) <= RR2) alive = false;
        am = __ballot(alive);
        am &= ~((i < 63) ? ((1ull << (i + 1)) - 1ull) : ~0ull);
      }
      if (lane == 0) sK = Kl;
    }
    __syncthreads();
  }
  if (threadIdx.x == 0) keptCntSeg[s] = (sK < KSEG) ? sK : KSEG;
}

// unify per-segment kept lists (segment-major; order within segment = greedy order)
__global__ void k_merge(int nseg, const float4* __restrict__ segKeptCand,
                        const int* __restrict__ segKeptIdx, const int* __restrict__ keptCntSeg,
                        float4* __restrict__ keptCand, int* __restrict__ keptIdx,
                        int* __restrict__ segKeptStart, int* __restrict__ segKeptCnt,
                        int* counters) {
  __shared__ int pre[NSEG_MAX + 1];
  if (threadIdx.x == 0) {
    int acc = 0;
    for (int s2 = 0; s2 < nseg; ++s2) {
      pre[s2] = acc;
      int cn = keptCntSeg[s2]; if (cn > KSEG) cn = KSEG;
      acc += cn;
    }
    pre[nseg] = acc;
    counters[C_KEPT] = (acc < KMAX) ? acc : KMAX;
  }
  __syncthreads();
  for (int s2 = 0; s2 < nseg; ++s2) {
    int cn = keptCntSeg[s2]; if (cn > KSEG) cn = KSEG;
    if (threadIdx.x == 0) { segKeptStart[s2] = pre[s2]; segKeptCnt[s2] = cn; }
    for (int j = threadIdx.x; j < cn; j += blockDim.x) {
      keptCand[pre[s2] + j] = segKeptCand[s2 * KSEG + j];
      keptIdx[pre[s2] + j] = segKeptIdx[s2 * KSEG + j];
    }
  }
}

// Each point -> FIRST kept (greedy order, own segment) within radius.
// Kept list + idx staged in LDS; x4-unrolled early-exit scan (wave-uniform j -> LDS broadcast);
// per-block LDS histogram -> one coalesced flush (no hot global atomics).
__global__ void __launch_bounds__(256) k_assign(
    const float* __restrict__ cc, const int* __restrict__ rs, int nrs, int N,
    const float4* __restrict__ keptCand, const int* __restrict__ keptIdx,
    const int* __restrict__ segKeptStart, const int* __restrict__ segKeptCnt,
    const int* __restrict__ counters,
    int* cntKept, int* countersW, int* __restrict__ assoInt,
    int* __restrict__ keptPos) {
  __shared__ float4 sk[ALDS];     // 32 KiB
  __shared__ int    sIx[ALDS];    // 8 KiB
  __shared__ int    shist[ALDS];  // 8 KiB
  __shared__ int    sUn;
  int Ktot = counters[C_KEPT];
  if (Ktot > KMAX) Ktot = KMAX;
  int Kl = Ktot < ALDS ? Ktot : ALDS;
  for (int j = threadIdx.x; j < Kl; j += blockDim.x) {
    sk[j] = keptCand[j];
    sIx[j] = keptIdx[j];
    shist[j] = 0;
  }
  if (threadIdx.x == 0) sUn = 0;
  __syncthreads();

  int i = blockIdx.x * blockDim.x + threadIdx.x;
  int bpos = -1, bidx = -1;
  bool active = i < N;
  if (active) {
    float4 p = make_float4(cc[3 * i], cc[3 * i + 1], cc[3 * i + 2], 0.f);
    int seg = 0;
    for (int t = 1; t < nrs - 1; ++t) seg += (i >= rs[t]) ? 1 : 0;
    int ks = segKeptStart[seg];
    int end = ks + segKeptCnt[seg];
    int lim = end < Kl ? end : Kl;
    int j = ks;
    for (; j + 3 < lim; j += 4) {     // 4 LDS reads per waitcnt -> 4x shorter chain
      bool h0 = dist2(sk[j], p) <= RR2;
      bool h1 = dist2(sk[j + 1], p) <= RR2;
      bool h2 = dist2(sk[j + 2], p) <= RR2;
      bool h3 = dist2(sk[j + 3], p) <= RR2;
      if (h0 | h1 | h2 | h3) { bpos = h0 ? j : h1 ? j + 1 : h2 ? j + 2 : j + 3; break; }
    }
    if (bpos < 0)
      for (; j < lim; ++j)
        if (dist2(sk[j], p) <= RR2) { bpos = j; break; }
    if (bpos < 0)                      // overflow tail beyond LDS (Ktot>ALDS): global
      for (; j < end; ++j)
        if (dist2(keptCand[j], p) <= RR2) { bpos = j; break; }
    if (bpos >= 0) {
      bidx = (bpos < Kl) ? sIx[bpos] : keptIdx[bpos];
      assoInt[i] = bidx;
      keptPos[i] = bpos;
      if (bpos < Kl) atomicAdd(&shist[bpos], 1);
      else atomicAdd(&cntKept[bpos], 1);
    } else {
      assoInt[i] = -1;
      keptPos[i] = -1;
      atomicAdd(&sUn, 1);
    }
  }
  __syncthreads();
  for (int j = threadIdx.x; j < Kl; j += blockDim.x) {
    int h = shist[j];
    if (h) atomicAdd(&cntKept[j], h);  // distinct addresses across lanes: parallel at L2
  }
  if (threadIdx.x == 0 && sUn) atomicAdd(&countersW[C_UN], sUn);
}

// rank kept by original index (asso values ascending); group 0 = unassigned if present
__global__ void k_rank(const int* __restrict__ keptIdx, int* counters,
                       const int* __restrict__ cntKept,
                       int* __restrict__ rankOfKept, int* __restrict__ groupCount) {
  __shared__ int sIdx[KMAX];   // 16 KiB
  int K = counters[C_KEPT];
  if (K > KMAX) K = KMAX;
  for (int j = threadIdx.x; j < K; j += blockDim.x) sIdx[j] = keptIdx[j];
  __syncthreads();
  int un = counters[C_UN];
  int hasUn = un > 0 ? 1 : 0;
  int gid = blockIdx.x * blockDim.x + threadIdx.x;
  int stride = gridDim.x * blockDim.x;
  if (gid == 0) {
    counters[C_HASUN] = hasUn;
    counters[C_G] = K + hasUn;
    if (hasUn) groupCount[0] = un;
  }
  for (int j = gid; j < K; j += stride) {
    int myIdx = sIdx[j];
    int r = hasUn;
    for (int j2 = 0; j2 < K; ++j2)
      r += (sIdx[j2] < myIdx) ? 1 : 0;
    rankOfKept[j] = r;
    groupCount[r] = cntKept[j];
  }
}

__global__ void k_pointrank(int N, const int* __restrict__ keptPos,
                            const int* __restrict__ rankOfKept,
                            const int* __restrict__ assoInt,
                            int* __restrict__ pointRank, float* __restrict__ outAsso) {
  int i = blockIdx.x * blockDim.x + threadIdx.x;
  if (i >= N) return;
  int p = keptPos[i];
  pointRank[i] = (p < 0) ? 0 : rankOfKept[p];
  outAsso[i] = (float)assoInt[i];
}

// parallel exclusive prefix over groupCount[0..G) (single block, 256 threads)
__global__ void k_scan(const int* __restrict__ counters, const int* __restrict__ groupCount,
                       int* __restrict__ starts) {
  __shared__ int partial[256];
  int G = counters[C_G];
  int t = threadIdx.x;
  const int PER = (KMAX + 2 + 255) / 256;
  int sum = 0;
  for (int q = 0; q < PER; ++q) {
    int idx = t * PER + q;
    if (idx < G) sum += groupCount[idx];
  }
  partial[t] = sum;
  __syncthreads();
  if (t == 0) {
    int acc = 0;
    for (int i = 0; i < 256; ++i) { int v = partial[i]; partial[i] = acc; acc += v; }
  }
  __syncthreads();
  int acc = partial[t];
  for (int q = 0; q < PER; ++q) {
    int idx = t * PER + q;
    if (idx < G) { starts[idx] = acc; acc += groupCount[idx]; }
  }
}

__global__ void k_psrs(int N, const int* __restrict__ counters, const int* __restrict__ starts,
                       float* __restrict__ outPsrs) {
  int p = blockIdx.x * blockDim.x + threadIdx.x;
  if (p > N) return;
  int G = counters[C_G];
  outPsrs[p] = (p < G) ? (float)starts[p] : (float)N;
}

// stable counting-sort scatter: one block per group, ballot prefix within chunks
__global__ void k_scatter(int N, const int* __restrict__ counters,
                          const int* __restrict__ pointRank, const int* __restrict__ starts,
                          int* __restrict__ order, float* __restrict__ outSids,
                          float* __restrict__ outBelongs) {
  int g = blockIdx.x;
  if (g >= counters[C_G]) return;
  int base = starts[g];
  __shared__ int wsum[4];
  int lane = threadIdx.x & 63, wv = threadIdx.x >> 6;
  for (int i0 = 0; i0 < N; i0 += 256) {
    int i = i0 + threadIdx.x;
    bool m = (i < N) && (pointRank[i] == g);
    unsigned long long bal = __ballot(m);
    int pw = __popcll(bal & ((1ull << lane) - 1ull));
    if (lane == 0) wsum[wv] = __popcll(bal);
    __syncthreads();
    int off = 0;
    for (int q = 0; q < wv; ++q) off += wsum[q];
    int tot = wsum[0] + wsum[1] + wsum[2] + wsum[3];
    if (m) {
      int pos = base + off + pw;
      order[pos] = i;
      outSids[pos] = (float)i;
      outBelongs[pos] = (float)g;
    }
    base += tot;
    __syncthreads();
  }
}

// flat grid-stride float4 row gather (F % 4 == 0 path)
__global__ void k_gather4(const float4* __restrict__ data4, const int* __restrict__ order,
                          int F4, int total4, float4* __restrict__ out4) {
  int stride = gridDim.x * blockDim.x;
  for (int idx = blockIdx.x * blockDim.x + threadIdx.x; idx < total4; idx += stride) {
    int row = idx / F4;
    int col = idx - row * F4;
    out4[idx] = data4[(size_t)order[row] * F4 + col];
  }
}

__global__ void k_gather(const float* __restrict__ data, const int* __restrict__ order,
                         int F, float* __restrict__ out) {
  int row = blockIdx.x;
  int src = order[row];
  for (int f = threadIdx.x; f < F; f += blockDim.x)
    out[(size_t)row * F + f] = data[(size_t)src * F + f];
}

extern "C" void kernel_launch(void* const* d_in, const int* in_sizes, int n_in,
                              void* d_out, int out_size, void* d_ws, size_t ws_size,
                              hipStream_t stream) {
  const float* data  = (const float*)d_in[0];
  const float* cc    = (const float*)d_in[1];
  const float* betas = (const float*)d_in[2];
  const int*   rs    = (const int*)d_in[3];
  int nrs = in_sizes[3];
  int N   = in_sizes[2];           // betas is (N,1)
  int F   = in_sizes[0] / N;       // 128
  int nseg = nrs - 1; if (nseg < 1) nseg = 1; if (nseg > NSEG_MAX) nseg = NSEG_MAX;

  float* out = (float*)d_out;
  float* outSdata   = out;
  float* outPsrs    = outSdata + (size_t)N * F;
  float* outSids    = outPsrs + (N + 1);
  float* outAsso    = outSids + N;
  float* outBelongs = outAsso + N;

  char* p = (char*)d_ws;
  auto alloc = [&](size_t bytes) { void* r = (void*)p; p += (bytes + 255) & ~(size_t)255; return r; };
  int*    counters     = (int*)alloc(64 * 4);
  float4* ucand        = (float4*)alloc((size_t)N * 16);
  int*    uidx         = (int*)alloc((size_t)N * 4);
  int*    ubkt         = (int*)alloc((size_t)N * 4);
  float4* scand        = (float4*)alloc((size_t)N * 16);
  int*    sidx         = (int*)alloc((size_t)N * 4);
  int*    bucketCnt    = (int*)alloc(NBTOT * 4);
  int*    bucketStart  = (int*)alloc((NBTOT + 1) * 4);
  int*    bucketFill   = (int*)alloc(NBTOT * 4);
  float4* segKeptCand  = (float4*)alloc((size_t)NSEG_MAX * KSEG * 16);
  int*    segKeptIdx   = (int*)alloc((size_t)NSEG_MAX * KSEG * 4);
  int*    keptCntSeg   = (int*)alloc(NSEG_MAX * 4);
  int*    segKeptStart = (int*)alloc(NSEG_MAX * 4);
  int*    segKeptCnt   = (int*)alloc(NSEG_MAX * 4);
  float4* keptCand     = (float4*)alloc(KMAX * 16);
  int*    keptIdx      = (int*)alloc(KMAX * 4);
  int*    rankOfKept   = (int*)alloc(KMAX * 4);
  int*    cntKept      = (int*)alloc(KMAX * 4);
  int*    groupCount   = (int*)alloc((KMAX + 2) * 4);
  int*    starts       = (int*)alloc((KMAX + 2) * 4);
  int*    assoInt      = (int*)alloc((size_t)N * 4);
  int*    keptPos      = (int*)alloc((size_t)N * 4);
  int*    pointRank    = (int*)alloc((size_t)N * 4);
  int*    order        = (int*)alloc((size_t)N * 4);

  int nb = (N + 255) / 256;

  k_init<<<(NBTOT + 255) / 256, 256, 0, stream>>>(counters, cntKept, groupCount,
                                                  bucketCnt, bucketFill);

  k_compact<<<nb, 256, 0, stream>>>(betas, cc, rs, nrs, N, ucand, uidx, ubkt,
                                    bucketCnt, &counters[C_U0]);

  k_bucketscan<<<1, 256, 0, stream>>>(bucketCnt, bucketStart);

  k_bucketscatter<<<nb, 256, 0, stream>>>(counters, ucand, uidx, ubkt,
                                          bucketStart, bucketFill, scand, sidx);

  k_bucketsort<<<NBTOT / 256, 256, 0, stream>>>(bucketCnt, bucketStart, scand, sidx);

  k_greedy<<<nseg, 1024, 0, stream>>>(scand, sidx, bucketStart,
                                      segKeptCand, segKeptIdx, keptCntSeg);

  k_merge<<<1, 256, 0, stream>>>(nseg, segKeptCand, segKeptIdx, keptCntSeg,
                                 keptCand, keptIdx, segKeptStart, segKeptCnt, counters);

  k_assign<<<nb, 256, 0, stream>>>(cc, rs, nrs, N, keptCand, keptIdx,
                                   segKeptStart, segKeptCnt, counters, cntKept, counters,
                                   assoInt, keptPos);

  k_rank<<<32, 256, 0, stream>>>(keptIdx, counters, cntKept, rankOfKept, groupCount);

  k_pointrank<<<nb, 256, 0, stream>>>(N, keptPos, rankOfKept, assoInt, pointRank, outAsso);

  k_scan<<<1, 256, 0, stream>>>(counters, groupCount, starts);

  k_psrs<<<(N + 256) / 256, 256, 0, stream>>>(N, counters, starts, outPsrs);

  k_scatter<<<KMAX + 1, 256, 0, stream>>>(N, counters, pointRank, starts, order,
                                          outSids, outBelongs);

  if (F % 4 == 0) {
    int F4 = F / 4;
    int total4 = N * F4;
    k_gather4<<<2048, 256, 0, stream>>>((const float4*)data, order, F4, total4,
                                        (float4*)outSdata);
  } else {
    k_gather<<<N, 128, 0, stream>>>(data, order, F, outSdata);
  }
}